// Round 14
// baseline (466.070 us; speedup 1.0000x reference)
//
#include <hip/hip_runtime.h>
#include <hip/hip_cooperative_groups.h>
namespace cg = cooperative_groups;

typedef __bf16 bf16;
typedef __bf16 bf16x8 __attribute__((ext_vector_type(8)));
typedef __bf16 bf16x4 __attribute__((ext_vector_type(4)));
typedef float  f32x4  __attribute__((ext_vector_type(4)));

#define GLD_LDS16(gp, lp) __builtin_amdgcn_global_load_lds( \
    (const __attribute__((address_space(1))) unsigned int*)(const void*)(gp), \
    (__attribute__((address_space(3))) unsigned int*)(void*)(lp), 16, 0, 0)

constexpr int BB = 4, SSEQ = 2048, DK = 1024, NH = 16, DH = 64;
constexpr int M = BB * SSEQ;                    // 8192 rows

constexpr size_t SZ_X = (size_t)M * DK * 2;     // 16 MiB
constexpr size_t SZ_W = (size_t)DK * DK * 2;    // 2 MiB
constexpr size_t OFF_QBF = 0;
constexpr size_t OFF_KBF = OFF_QBF + SZ_X;
constexpr size_t OFF_VBF = OFF_KBF + SZ_X;
constexpr size_t OFF_WQT = OFF_VBF + SZ_X;
constexpr size_t OFF_WKT = OFF_WQT + SZ_W;
constexpr size_t OFF_WVT = OFF_WKT + SZ_W;
constexpr size_t OFF_WUT = OFF_WVT + SZ_W;
constexpr size_t OFF_QH  = OFF_WUT + SZ_W;      // (B,S,1024) bf16 flat
constexpr size_t OFF_KH  = OFF_QH + SZ_X;       // (B,S,1024) bf16 flat
constexpr size_t OFF_VTH = OFF_KH + SZ_X;       // (B,H,64,S) bf16 (transposed)
constexpr size_t OFF_MRG = OFF_VTH + SZ_X;      // (B,S,1024) bf16

// R14: ONE cooperative kernel, 4 phases with grid.sync() between them.
// Rationale: R13 budget shows ~100us of the 310.5 not attributable to any
// dispatch (top-5 bounds every non-attn kernel <73us; realistic sum ~192us).
// A single dispatch directly measures GPU-busy time and removes 3 launch
// boundaries. Phases grid-stride over gridDim so any co-resident capacity
// works. attn = R7-form softmax (fits the (512,2)=128-reg cap spill-free;
// R8 proved the ones-MFMA form needs ~136 regs -> spills at this cap).

struct GArg {
    const bf16* A; const bf16* BT; const float* bias; void* out; int mode; float oscale;
};

struct MegaArg {
    const float *q, *k, *v, *wq, *wk, *wv, *wu;
    const float *bq, *bk, *bv, *bu;
    bf16 *qbf, *kbf, *vbf, *wqt, *wkt, *wvt, *wut, *qh, *kh, *vth, *mrg;
    float* out;
};

// ---------------------------------------------------------------- GEMM tile
// R7/R13 schedule (verified race-free): 8-wave 128x128x64 tile, raw s_barrier
// + counted vmcnt(4) (T3+T4), T2 XOR-swizzle via pre-swizzled global source,
// T5 setprio. BAR1 after vmcnt(4): tile t landed. BAR2 after lgkm(0): all
// reads of buf[cur] retired -> stage(t+2) may overwrite. Back-to-back tiles
// are safe: every LDS read of a buffer retires before that tile's BAR2.
__device__ __forceinline__ void gemm_tile(const GArg& g, int x, int tid, char* arena) {
    bf16 (*As)[128 * 64] = (bf16(*)[128 * 64])arena;
    bf16 (*Bs)[128 * 64] = (bf16(*)[128 * 64])(arena + 32768);
    const int lane = tid & 63, wv = tid >> 6;    // 8 waves
    const int wm = (wv >> 2) * 64;               // 0,64
    const int wn = (wv & 3) * 32;                // 0,32,64,96
    const int cl = lane & 15, qd = lane >> 4;
    const int rowbase = ((x & 7) * 8 + ((x >> 3) & 7)) * 128;
    const int colbase = (x >> 6) * 128;

    f32x4 acc[4][2];
#pragma unroll
    for (int i = 0; i < 4; i++)
#pragma unroll
        for (int j = 0; j < 2; j++) acc[i][j] = f32x4{0.f, 0.f, 0.f, 0.f};

    const bool swapped = (g.mode == 1);

    auto stage = [&](int t, int buf) {
#pragma unroll
        for (int c = 0; c < 2; c++) {
            int L = c * 512 + tid;
            int row = L >> 3, s16 = L & 7;
            int sc = s16 ^ (row & 7);
            GLD_LDS16(g.A + (size_t)(rowbase + row) * DK + t * 64 + sc * 8, &As[buf][L * 8]);
        }
#pragma unroll
        for (int c = 0; c < 2; c++) {
            int L = c * 512 + tid;
            int row = L >> 3, s16 = L & 7;
            int sc = s16 ^ (row & 7);
            GLD_LDS16(g.BT + (size_t)(colbase + row) * DK + t * 64 + sc * 8, &Bs[buf][L * 8]);
        }
    };

    stage(0, 0);
    stage(1, 1);

    auto ktile = [&](int t, int cur, bool doStage, bool last) __attribute__((always_inline)) {
        if (last) asm volatile("s_waitcnt vmcnt(0)" ::: "memory");
        else      asm volatile("s_waitcnt vmcnt(4)" ::: "memory");
        asm volatile("s_barrier" ::: "memory");          // tile t visible everywhere
        bf16x8 a0[4], b0[2], a1[4], b1[2];
#pragma unroll
        for (int i = 0; i < 4; i++)
            a0[i] = *(const bf16x8*)&As[cur][(wm + i * 16 + cl) * 64 + ((qd ^ (cl & 7)) * 8)];
#pragma unroll
        for (int j = 0; j < 2; j++)
            b0[j] = *(const bf16x8*)&Bs[cur][(wn + j * 16 + cl) * 64 + ((qd ^ (cl & 7)) * 8)];
#pragma unroll
        for (int i = 0; i < 4; i++)
            a1[i] = *(const bf16x8*)&As[cur][(wm + i * 16 + cl) * 64 + (((4 + qd) ^ (cl & 7)) * 8)];
#pragma unroll
        for (int j = 0; j < 2; j++)
            b1[j] = *(const bf16x8*)&Bs[cur][(wn + j * 16 + cl) * 64 + (((4 + qd) ^ (cl & 7)) * 8)];
        __builtin_amdgcn_s_setprio(1);
        if (swapped) {
#pragma unroll
            for (int i = 0; i < 4; i++)
#pragma unroll
                for (int j = 0; j < 2; j++)
                    acc[i][j] = __builtin_amdgcn_mfma_f32_16x16x32_bf16(b0[j], a0[i], acc[i][j], 0, 0, 0);
        } else {
#pragma unroll
            for (int i = 0; i < 4; i++)
#pragma unroll
                for (int j = 0; j < 2; j++)
                    acc[i][j] = __builtin_amdgcn_mfma_f32_16x16x32_bf16(a0[i], b0[j], acc[i][j], 0, 0, 0);
        }
        __builtin_amdgcn_s_setprio(0);
        asm volatile("s_waitcnt lgkmcnt(0)" ::: "memory");  // ALL reads of buf[cur] retired
        asm volatile("s_barrier" ::: "memory");             // buffer free for restage
        if (doStage) stage(t + 2, cur);                     // in flight during k1 MFMAs
        __builtin_amdgcn_s_setprio(1);
        if (swapped) {
#pragma unroll
            for (int i = 0; i < 4; i++)
#pragma unroll
                for (int j = 0; j < 2; j++)
                    acc[i][j] = __builtin_amdgcn_mfma_f32_16x16x32_bf16(b1[j], a1[i], acc[i][j], 0, 0, 0);
        } else {
#pragma unroll
            for (int i = 0; i < 4; i++)
#pragma unroll
                for (int j = 0; j < 2; j++)
                    acc[i][j] = __builtin_amdgcn_mfma_f32_16x16x32_bf16(a1[i], b1[j], acc[i][j], 0, 0, 0);
        }
        __builtin_amdgcn_s_setprio(0);
    };

    for (int t = 0; t < 14; ++t) ktile(t, t & 1, true, false);
    ktile(14, 0, false, false);
    ktile(15, 1, false, true);

    if (g.mode == 2) {
        float* out = (float*)g.out;
#pragma unroll
        for (int i = 0; i < 4; i++)
#pragma unroll
            for (int j = 0; j < 2; j++)
#pragma unroll
                for (int r = 0; r < 4; r++) {
                    int row = rowbase + wm + i * 16 + qd * 4 + r;
                    int col = colbase + wn + j * 16 + cl;
                    out[(size_t)row * DK + col] = (acc[i][j][r] + g.bias[col]) * g.oscale;
                }
    } else if (g.mode == 0) {
        bf16* out = (bf16*)g.out;
#pragma unroll
        for (int i = 0; i < 4; i++)
#pragma unroll
            for (int j = 0; j < 2; j++)
#pragma unroll
                for (int r = 0; r < 4; r++) {
                    int row = rowbase + wm + i * 16 + qd * 4 + r;
                    int col = colbase + wn + j * 16 + cl;
                    float v = (acc[i][j][r] + g.bias[col]) * g.oscale;
                    out[(size_t)row * DK + col] = (bf16)v;
                }
    } else {
        // transposed epilogue: acc holds C^T tile — rows = cols(h,d), cols = rows(s)
        bf16* out = (bf16*)g.out;   // (B,H,64,S)
#pragma unroll
        for (int i = 0; i < 4; i++)
#pragma unroll
            for (int j = 0; j < 2; j++)
#pragma unroll
                for (int r = 0; r < 4; r++) {
                    int colg = colbase + wn + j * 16 + qd * 4 + r;   // h*64+d
                    int rowg = rowbase + wm + i * 16 + cl;           // b*2048+s
                    int b_ = rowg >> 11, s_ = rowg & 2047;
                    float v = (acc[i][j][r] + g.bias[colg]) * g.oscale;
                    out[((size_t)(b_ * NH + (colg >> 6)) * DH + (colg & 63)) * SSEQ + s_] = (bf16)v;
                }
    }
}

// ---------------------------------------------------------------- attn (one logical 256-thr block)
// R7-form (79.2us standalone): key-permuted K staging -> full-rate PV; fixed-max
// exp2 softmax with VALU ps accumulation + shfl epilogue (fits 128-reg cap).
__device__ __forceinline__ void attn_logical(int W, int ltid, char* slice, const MegaArg& A) {
    bf16 (*Ks)[64 * 64]  = (bf16(*)[64 * 64])slice;
    bf16 (*VTs)[64 * 64] = (bf16(*)[64 * 64])(slice + 16384);
    const int lane = ltid & 63, w = ltid >> 6;
    const int cl = lane & 15, qd = lane >> 4;
    const int xcd = W & 7, slot = W >> 3;
    const int bh = xcd * 8 + (slot & 7);
    const int qt = slot >> 3;            // 0..15
    const int b_ = bh >> 4, h_ = bh & 15;
    const int qbase = qt * 128;
    const bf16* Qb = A.qh + ((size_t)b_ * SSEQ) * DK + h_ * DH;
    const bf16* Kb = A.kh + ((size_t)b_ * SSEQ) * DK + h_ * DH;
    const bf16* Vb = A.vth + (size_t)bh * DH * SSEQ;

    bf16x8 qf[2][2];
#pragma unroll
    for (int mi = 0; mi < 2; mi++) {
        int q = qbase + w * 32 + mi * 16 + cl;
        qf[mi][0] = *(const bf16x8*)&Qb[(size_t)q * DK + qd * 8];
        qf[mi][1] = *(const bf16x8*)&Qb[(size_t)q * DK + 32 + qd * 8];
    }
    f32x4 O[2][4];
#pragma unroll
    for (int mi = 0; mi < 2; mi++)
#pragma unroll
        for (int jv = 0; jv < 4; jv++) O[mi][jv] = f32x4{0.f, 0.f, 0.f, 0.f};
    float ps[2] = {0.f, 0.f};

    auto stage = [&](int kt, int buf) {
#pragma unroll
        for (int c = 0; c < 2; c++) {
            int L = c * 256 + ltid;
            int row = L >> 3, lc = (L & 7) ^ (row & 7);
            int prow = ((row >> 5) << 5) | (((row >> 2) & 3) << 3)
                     | (((row >> 4) & 1) << 2) | (row & 3);      // pi(row)
            GLD_LDS16(Kb + (size_t)(kt * 64 + prow) * DK + lc * 8, &Ks[buf][L * 8]);
        }
#pragma unroll
        for (int c = 0; c < 2; c++) {
            int L = c * 256 + ltid;
            int row = L >> 3, lc = (L & 7) ^ (row & 7);
            GLD_LDS16(Vb + (size_t)row * SSEQ + kt * 64 + lc * 8, &VTs[buf][L * 8]);
        }
    };
    stage(0, 0);

    for (int kt = 0; kt < 32; kt++) {
        const int buf = kt & 1;
        __syncthreads();                 // block-wide (both halves in lockstep)
        if (kt + 1 < 32) stage(kt + 1, buf ^ 1);

        bf16x8 pf8[2][2];
#pragma unroll
        for (int jt = 0; jt < 4; jt++) {
            bf16x8 kf0 = *(const bf16x8*)&Ks[buf][(jt * 16 + cl) * 64 + ((qd ^ (cl & 7)) * 8)];
            bf16x8 kf1 = *(const bf16x8*)&Ks[buf][(jt * 16 + cl) * 64 + (((4 + qd) ^ (cl & 7)) * 8)];
#pragma unroll
            for (int mi = 0; mi < 2; mi++) {
                __builtin_amdgcn_s_setprio(1);
                f32x4 S = __builtin_amdgcn_mfma_f32_16x16x32_bf16(kf0, qf[mi][0],
                                                                  f32x4{0.f, 0.f, 0.f, 0.f}, 0, 0, 0);
                S = __builtin_amdgcn_mfma_f32_16x16x32_bf16(kf1, qf[mi][1], S, 0, 0, 0);
                __builtin_amdgcn_s_setprio(0);
                float s = 0.f;
#pragma unroll
                for (int r = 0; r < 4; r++) {
                    float p = __builtin_amdgcn_exp2f(S[r]);
                    s += p;
                    pf8[mi][jt >> 1][(jt & 1) * 4 + r] = (bf16)p;
                }
                ps[mi] += s;
            }
        }

        __builtin_amdgcn_s_setprio(1);
#pragma unroll
        for (int g = 0; g < 2; g++) {
#pragma unroll
            for (int jv = 0; jv < 4; jv++) {
                bf16x8 vf = *(const bf16x8*)&VTs[buf][(jv * 16 + cl) * 64 +
                                (((g * 4 + qd) ^ (cl & 7)) * 8)];
#pragma unroll
                for (int mi = 0; mi < 2; mi++)
                    O[mi][jv] = __builtin_amdgcn_mfma_f32_16x16x32_bf16(vf, pf8[mi][g], O[mi][jv], 0, 0, 0);
            }
        }
        __builtin_amdgcn_s_setprio(0);
    }

#pragma unroll
    for (int mi = 0; mi < 2; mi++) {
        float t = ps[mi];
        t += __shfl_xor(t, 16);
        t += __shfl_xor(t, 32);
        float inv = 1.0f / t;
        int q = qbase + w * 32 + mi * 16 + cl;
        size_t ro = ((size_t)(b_ * SSEQ + q)) * DK + h_ * DH;
#pragma unroll
        for (int jv = 0; jv < 4; jv++) {
            bf16x4 o4;
#pragma unroll
            for (int r = 0; r < 4; r++) o4[r] = (bf16)(O[mi][jv][r] * inv);
            *(bf16x4*)&A.mrg[ro + jv * 16 + qd * 4] = o4;
        }
    }
}

// ---------------------------------------------------------------- mega kernel
__global__ __launch_bounds__(512, 2) void mega(MegaArg A) {
    __shared__ __attribute__((aligned(16))) char arena[65536];
    const int tid = threadIdx.x;
    const int half = tid >> 8, ltid = tid & 255;
    const int bid = (int)blockIdx.x, NB = (int)gridDim.x;
    cg::grid_group grid = cg::this_grid();

    // ---- phase 0a: weight transposes (1024 logical 64x64 tiles, 2 per block-iter)
    {
        float (*t)[65] = (float(*)[65])(arena + half * 32768);
        int tx = ltid & 63, ty = ltid >> 6;
        for (int wt0 = bid; wt0 < 512; wt0 += NB) {
            int wt = wt0 * 2 + half;
            int z = wt >> 8, r_ = wt & 255;
            int by = (r_ >> 4) * 64, bx = (r_ & 15) * 64;
            const float* w = (z == 0) ? A.wq : (z == 1) ? A.wk : (z == 2) ? A.wv : A.wu;
            bf16* o        = (z == 0) ? A.wqt : (z == 1) ? A.wkt : (z == 2) ? A.wvt : A.wut;
            __syncthreads();
#pragma unroll
            for (int rr = 0; rr < 16; rr++) {
                int row = ty * 16 + rr;
                t[row][tx] = w[(size_t)(by + row) * DK + bx + tx];
            }
            __syncthreads();
#pragma unroll
            for (int rr = 0; rr < 16; rr++) {
                int row2 = ty * 16 + rr;
                o[(size_t)(bx + row2) * DK + by + tx] = (bf16)t[tx][row2];
            }
        }
    }
    // ---- phase 0b: q/k/v f32 -> bf16
    {
        const size_t N4 = (size_t)M * DK / 4;
        const float4* srcs[3] = {(const float4*)A.q, (const float4*)A.k, (const float4*)A.v};
        bf16x4* dsts[3] = {(bf16x4*)A.qbf, (bf16x4*)A.kbf, (bf16x4*)A.vbf};
#pragma unroll
        for (int z = 0; z < 3; z++) {
            for (size_t i = (size_t)bid * 512 + tid; i < N4; i += (size_t)NB * 512) {
                float4 val = srcs[z][i];
                bf16x4 o = { (bf16)val.x, (bf16)val.y, (bf16)val.z, (bf16)val.w };
                dsts[z][i] = o;
            }
        }
    }
    grid.sync();

    // ---- phase 1: QKV projections (1536 logical tiles; grid=512 -> z=0,1,2 same x)
    {
        GArg gq{A.qbf, A.wqt, A.bq, (void*)A.qh, 0, 0.18033688011112043f};
        GArg gk{A.kbf, A.wkt, A.bk, (void*)A.kh, 0, 1.0f};
        GArg gv{A.vbf, A.wvt, A.bv, (void*)A.vth, 1, 1.0f};
        for (int lt = bid; lt < 1536; lt += NB) {
            int z = lt >> 9, x = lt & 511;
            gemm_tile(z == 0 ? gq : z == 1 ? gk : gv, x, tid, arena);
        }
    }
    grid.sync();

    // ---- phase 2: attention (1024 logical 256-thr blocks, 2 per block-iter)
    for (int W0 = bid; W0 < 512; W0 += NB)
        attn_logical(W0 + 512 * half, ltid, arena + half * 32768, A);
    grid.sync();

    // ---- phase 3: output projection (512 logical tiles)
    {
        GArg go{A.mrg, A.wut, A.bu, (void*)A.out, 2, 1.0f};
        for (int x = bid; x < 512; x += NB)
            gemm_tile(go, x, tid, arena);
    }
}

// ---------------------------------------------------------------- launch
extern "C" void kernel_launch(void* const* d_in, const int* in_sizes, int n_in,
                              void* d_out, int out_size, void* d_ws, size_t ws_size,
                              hipStream_t stream) {
    char* ws = (char*)d_ws;
    MegaArg ma;
    ma.q  = (const float*)d_in[0];
    ma.k  = (const float*)d_in[1];
    ma.v  = (const float*)d_in[2];
    ma.wq = (const float*)d_in[3];
    ma.bq = (const float*)d_in[4];
    ma.wk = (const float*)d_in[5];
    ma.bk = (const float*)d_in[6];
    ma.wv = (const float*)d_in[7];
    ma.bv = (const float*)d_in[8];
    ma.wu = (const float*)d_in[9];
    ma.bu = (const float*)d_in[10];
    ma.qbf = (bf16*)(ws + OFF_QBF);
    ma.kbf = (bf16*)(ws + OFF_KBF);
    ma.vbf = (bf16*)(ws + OFF_VBF);
    ma.wqt = (bf16*)(ws + OFF_WQT);
    ma.wkt = (bf16*)(ws + OFF_WKT);
    ma.wvt = (bf16*)(ws + OFF_WVT);
    ma.wut = (bf16*)(ws + OFF_WUT);
    ma.qh  = (bf16*)(ws + OFF_QH);
    ma.kh  = (bf16*)(ws + OFF_KH);
    ma.vth = (bf16*)(ws + OFF_VTH);
    ma.mrg = (bf16*)(ws + OFF_MRG);
    ma.out = (float*)d_out;

    int nb = 0;
    if (hipOccupancyMaxActiveBlocksPerMultiprocessor(&nb, (const void*)mega, 512, 0)
            != hipSuccess || nb < 1)
        nb = 1;
    int gridsz = nb * 256;
    if (gridsz > 512) gridsz = 512;

    void* args[] = { (void*)&ma };
    hipLaunchCooperativeKernel((void*)mega, dim3(gridsz), dim3(512), args, 0, stream);
}